// Round 4
// baseline (302.332 us; speedup 1.0000x reference)
//
#include <hip/hip_runtime.h>
#include <math.h>

#define NB 1024      // batch (queries)
#define NP 512       // pool size
#define NH 1024      // hidden
#define NK 8         // topk
#define NL 32        // pre_seq_len
#define NBK (NB * NK)
#define SLICE (NL * NH)   // floats per output slice (32768 = 128 KB)
#define EPSF 1e-8f

typedef float f32x4 __attribute__((ext_vector_type(4)));
typedef short s16x8 __attribute__((ext_vector_type(8)));
typedef unsigned short u16;

// ---- manual bf16 helpers (RNE), header-type-free ----
__device__ __forceinline__ u16 f2bf(float x) {
  union { float f; unsigned u; } v; v.f = x;
  unsigned r = (v.u + 0x7FFFu + ((v.u >> 16) & 1u)) >> 16;
  return (u16)r;
}
__device__ __forceinline__ float bf2f(u16 b) {
  union { unsigned u; float f; } v; v.u = ((unsigned)b) << 16;
  return v.f;
}

// ---------------- Kernel 1: normalize + 3-term bf16 split ----------------
// One block per row (0..1023 = querys, 1024..1535 = prompts_key).
// Writes 3 bf16 planes per matrix: X3[t][row][h], t=0,1,2 (x ~= x0+x1+x2).
__global__ __launch_bounds__(256) void convert_kernel(
    const float* __restrict__ q, const float* __restrict__ pk,
    u16* __restrict__ Q3, u16* __restrict__ K3) {
  const int row = blockIdx.x;
  const int tid = threadIdx.x;
  const float* src;
  u16* dst;      // plane-0 base for this row
  int plane;     // elements per plane
  if (row < NB) {
    src = q + (size_t)row * NH;
    dst = Q3 + (size_t)row * NH;
    plane = NB * NH;
  } else {
    src = pk + (size_t)(row - NB) * NH;
    dst = K3 + (size_t)(row - NB) * NH;
    plane = NP * NH;
  }
  float4 v = ((const float4*)src)[tid];  // 256 threads x float4 = 1024 floats
  float s = v.x * v.x + v.y * v.y + v.z * v.z + v.w * v.w;
#pragma unroll
  for (int off = 32; off; off >>= 1) s += __shfl_xor(s, off);
  __shared__ float ws[4];
  if ((tid & 63) == 0) ws[tid >> 6] = s;
  __syncthreads();
  float total = ws[0] + ws[1] + ws[2] + ws[3];
  const float inv = 1.f / fmaxf(sqrtf(total), EPSF);

  float x[4] = {v.x * inv, v.y * inv, v.z * inv, v.w * inv};
  u16 t0[4], t1[4], t2[4];
#pragma unroll
  for (int i = 0; i < 4; ++i) {
    float f = x[i];
    u16 b0 = f2bf(f);        float r1 = f - bf2f(b0);
    u16 b1 = f2bf(r1);       float r2 = r1 - bf2f(b1);
    u16 b2 = f2bf(r2);
    t0[i] = b0; t1[i] = b1; t2[i] = b2;
  }
  ushort4* d0 = (ushort4*)(dst + tid * 4);
  ushort4* d1 = (ushort4*)(dst + plane + tid * 4);
  ushort4* d2 = (ushort4*)(dst + 2 * plane + tid * 4);
  *d0 = make_ushort4(t0[0], t0[1], t0[2], t0[3]);
  *d1 = make_ushort4(t1[0], t1[1], t1[2], t1[3]);
  *d2 = make_ushort4(t2[0], t2[1], t2[2], t2[3]);
}

// ---------------- Kernel 2: sim via bf16 MFMA, 6-term split product ----------------
// Block = 4 waves, each wave one 16x16 output tile; block tile 32x32.
// A-frag: lane holds row (lane&15), k = (lane>>4)*8 + i. B symmetric (col).
// C/D: col = lane&15, row = (lane>>4)*4 + reg  [m89-verified].
__global__ __launch_bounds__(256) void sim_mfma_kernel(
    const u16* __restrict__ Q3, const u16* __restrict__ K3,
    float* __restrict__ sim) {
  const int bm = blockIdx.x;   // 32 query tiles of 32
  const int bn = blockIdx.y;   // 16 pool tiles of 32
  const int wave = threadIdx.x >> 6;
  const int lane = threadIdx.x & 63;
  const int r0 = bm * 32 + (wave & 1) * 16;
  const int c0 = bn * 32 + (wave >> 1) * 16;
  const int koff = (lane >> 4) * 8;

  const u16* aB = Q3 + (size_t)(r0 + (lane & 15)) * NH + koff;
  const u16* bB = K3 + (size_t)(c0 + (lane & 15)) * NH + koff;
  const int QP = NB * NH, KP = NP * NH;

  f32x4 acc0 = {0.f, 0.f, 0.f, 0.f};
  f32x4 acc1 = {0.f, 0.f, 0.f, 0.f};

  for (int kc = 0; kc < NH; kc += 64) {
    // chunk A (kc) and chunk B (kc+32), independent accumulator chains
    s16x8 a00 = *(const s16x8*)(aB + kc);
    s16x8 a01 = *(const s16x8*)(aB + QP + kc);
    s16x8 a02 = *(const s16x8*)(aB + 2 * QP + kc);
    s16x8 b00 = *(const s16x8*)(bB + kc);
    s16x8 b01 = *(const s16x8*)(bB + KP + kc);
    s16x8 b02 = *(const s16x8*)(bB + 2 * KP + kc);
    s16x8 a10 = *(const s16x8*)(aB + kc + 32);
    s16x8 a11 = *(const s16x8*)(aB + QP + kc + 32);
    s16x8 a12 = *(const s16x8*)(aB + 2 * QP + kc + 32);
    s16x8 b10 = *(const s16x8*)(bB + kc + 32);
    s16x8 b11 = *(const s16x8*)(bB + KP + kc + 32);
    s16x8 b12 = *(const s16x8*)(bB + 2 * KP + kc + 32);

    acc0 = __builtin_amdgcn_mfma_f32_16x16x32_bf16(a00, b00, acc0, 0, 0, 0);
    acc1 = __builtin_amdgcn_mfma_f32_16x16x32_bf16(a10, b10, acc1, 0, 0, 0);
    acc0 = __builtin_amdgcn_mfma_f32_16x16x32_bf16(a00, b01, acc0, 0, 0, 0);
    acc1 = __builtin_amdgcn_mfma_f32_16x16x32_bf16(a10, b11, acc1, 0, 0, 0);
    acc0 = __builtin_amdgcn_mfma_f32_16x16x32_bf16(a01, b00, acc0, 0, 0, 0);
    acc1 = __builtin_amdgcn_mfma_f32_16x16x32_bf16(a11, b10, acc1, 0, 0, 0);
    acc0 = __builtin_amdgcn_mfma_f32_16x16x32_bf16(a01, b01, acc0, 0, 0, 0);
    acc1 = __builtin_amdgcn_mfma_f32_16x16x32_bf16(a11, b11, acc1, 0, 0, 0);
    acc0 = __builtin_amdgcn_mfma_f32_16x16x32_bf16(a00, b02, acc0, 0, 0, 0);
    acc1 = __builtin_amdgcn_mfma_f32_16x16x32_bf16(a10, b12, acc1, 0, 0, 0);
    acc0 = __builtin_amdgcn_mfma_f32_16x16x32_bf16(a02, b00, acc0, 0, 0, 0);
    acc1 = __builtin_amdgcn_mfma_f32_16x16x32_bf16(a12, b10, acc1, 0, 0, 0);
  }

#pragma unroll
  for (int i = 0; i < 4; ++i) {
    int row = r0 + (lane >> 4) * 4 + i;
    int col = c0 + (lane & 15);
    sim[(size_t)row * NP + col] = acc0[i] + acc1[i];
  }
}

// ---------------- Kernel 3: per-row top-8 (sorted desc, tie -> lower index) ----------------
__global__ __launch_bounds__(256) void topk_kernel(
    const float* __restrict__ sim, float* __restrict__ top_sim, int* __restrict__ top_idx) {
  int row = blockIdx.x * 4 + (threadIdx.x >> 6);
  int lane = threadIdx.x & 63;
  if (row >= NB) return;

  float vals[NP / 64];
#pragma unroll
  for (int i = 0; i < NP / 64; ++i) vals[i] = sim[(size_t)row * NP + lane + i * 64];

  for (int t = 0; t < NK; ++t) {
    float bv = vals[0];
    int bi = 0;
#pragma unroll
    for (int i = 1; i < NP / 64; ++i) {
      if (vals[i] > bv) { bv = vals[i]; bi = i; }
    }
    float v = bv;
    int p = lane + bi * 64;
#pragma unroll
    for (int off = 32; off; off >>= 1) {
      float ov = __shfl_xor(v, off);
      int op = __shfl_xor(p, off);
      if (ov > v || (ov == v && op < p)) { v = ov; p = op; }
    }
    if (lane == 0) {
      top_sim[row * NK + t] = v;
      top_idx[row * NK + t] = p;
    }
    if ((p & 63) == lane) {
      int wi = p >> 6;
#pragma unroll
      for (int i = 0; i < NP / 64; ++i)
        if (i == wi) vals[i] = -INFINITY;
    }
  }
}

// ---------------- Kernel 3.5: counting-sort permutation of 0..8191 by idx[] ----------------
__global__ __launch_bounds__(512) void sortperm_kernel(
    const int* __restrict__ idx, int* __restrict__ order) {
  __shared__ int hist[NP];
  __shared__ int offs[NP];
  const int t = threadIdx.x;
  hist[t] = 0;
  __syncthreads();
  for (int i = t; i < NBK; i += 512) atomicAdd(&hist[idx[i]], 1);
  __syncthreads();
  int sum = 0;
  for (int i = 0; i < t; ++i) sum += hist[i];
  offs[t] = sum;
  __syncthreads();
  for (int i = t; i < NBK; i += 512) {
    int p = idx[i];
    int pos = atomicAdd(&offs[p], 1);
    order[pos] = i;
  }
}

// ---------------- Kernel 4: gather in p-sorted dispatch order ----------------
__global__ __launch_bounds__(256) void gather_sorted(
    const float* __restrict__ prompts, const int* __restrict__ idx,
    const int* __restrict__ order, float* __restrict__ out, int skip_slice) {
  const int j = order[blockIdx.x];
  if (j == skip_slice) return;
  const int p = idx[j];
  const f32x4* __restrict__ src = (const f32x4*)(prompts + (size_t)p * SLICE);
  f32x4* __restrict__ dst = (f32x4*)(out + (size_t)j * SLICE);
  const int t = threadIdx.x;
#pragma unroll
  for (int i = 0; i < (SLICE / 4) / 256; ++i) {
    f32x4 v = src[t + i * 256];
    __builtin_nontemporal_store(v, &dst[t + i * 256]);
  }
}

// ---------------- Kernel 4b (fallback only): copy the scratch-holding slice ----------------
__global__ __launch_bounds__(256) void gather_tail(
    const float* __restrict__ prompts, const int* __restrict__ idx,
    float* __restrict__ out, int j) {
  const int p = idx[j];
  __syncthreads();
  const f32x4* __restrict__ src = (const f32x4*)(prompts + (size_t)p * SLICE);
  f32x4* __restrict__ dst = (f32x4*)(out + (size_t)j * SLICE);
  const int t = threadIdx.x;
#pragma unroll
  for (int i = 0; i < (SLICE / 4) / 256; ++i) {
    f32x4 v = src[t + i * 256];
    __builtin_nontemporal_store(v, &dst[t + i * 256]);
  }
}

extern "C" void kernel_launch(void* const* d_in, const int* in_sizes, int n_in,
                              void* d_out, int out_size, void* d_ws, size_t ws_size,
                              hipStream_t stream) {
  const float* querys = (const float*)d_in[0];       // [1024,1024]
  const float* prompts_key = (const float*)d_in[1];  // [512,1024]
  const float* prompts = (const float*)d_in[2];      // [512,32,1024]
  float* out = (float*)d_out;

  const size_t GATHER = (size_t)NBK * SLICE;  // 268435456 floats
  float* top_sim = out + GATHER;              // real output tail [8192]

  // Front scratch (consumed before gather overwrites slices 0..21):
  //   sim  [1024*512] f32      at out + 0
  //   Q3   [3*1024*1024] bf16  at out + 524288   (1572864 floats of space)
  //   K3   [3*512*1024]  bf16  at out + 2097152  (786432 floats of space)
  float* sim = out;
  u16* Q3 = (u16*)(out + 524288);
  u16* K3 = (u16*)(out + 2097152);

  // idx[8192] + order[8192]: prefer d_ws; else carve from slice 8190.
  int* idx;
  int* order;
  int skip_slice;
  if (ws_size >= 2 * NBK * sizeof(int)) {
    idx = (int*)d_ws;
    order = idx + NBK;
    skip_slice = -1;
  } else {
    idx = (int*)(out + (size_t)(NBK - 2) * SLICE);
    order = idx + NBK;
    skip_slice = NBK - 2;
  }

  convert_kernel<<<NB + NP, 256, 0, stream>>>(querys, prompts_key, Q3, K3);

  dim3 gsim(NB / 32, NP / 32);  // 32 x 16
  sim_mfma_kernel<<<gsim, 256, 0, stream>>>(Q3, K3, sim);

  topk_kernel<<<NB / 4, 256, 0, stream>>>(sim, top_sim, idx);

  sortperm_kernel<<<1, 512, 0, stream>>>(idx, order);

  gather_sorted<<<NBK, 256, 0, stream>>>(prompts, idx, order, out, skip_slice);

  if (skip_slice >= 0) {
    gather_tail<<<1, 256, 0, stream>>>(prompts, idx, out, skip_slice);
  }
}

// Round 5
// 292.858 us; speedup vs baseline: 1.0324x; 1.0324x over previous
//
#include <hip/hip_runtime.h>
#include <math.h>

#define NB 1024      // batch (queries)
#define NP 512       // pool size
#define NH 1024      // hidden
#define NK 8         // topk
#define NL 32        // pre_seq_len
#define NBK (NB * NK)
#define SLICE (NL * NH)   // floats per output slice (32768 = 128 KB)
#define EPSF 1e-8f

typedef float f32x4 __attribute__((ext_vector_type(4)));
typedef short s16x8 __attribute__((ext_vector_type(8)));
typedef unsigned short u16;

// ---- manual bf16 helpers (RNE) ----
__device__ __forceinline__ u16 f2bf(float x) {
  union { float f; unsigned u; } v; v.f = x;
  unsigned r = (v.u + 0x7FFFu + ((v.u >> 16) & 1u)) >> 16;
  return (u16)r;
}
__device__ __forceinline__ float bf2f(u16 b) {
  union { unsigned u; float f; } v; v.u = ((unsigned)b) << 16;
  return v.f;
}

// ---------------- Kernel 1: normalize + 3-term bf16 split ----------------
__global__ __launch_bounds__(256) void convert_kernel(
    const float* __restrict__ q, const float* __restrict__ pk,
    u16* __restrict__ Q3, u16* __restrict__ K3) {
  const int row = blockIdx.x;
  const int tid = threadIdx.x;
  const float* src;
  u16* dst;
  int plane;
  if (row < NB) {
    src = q + (size_t)row * NH;
    dst = Q3 + (size_t)row * NH;
    plane = NB * NH;
  } else {
    src = pk + (size_t)(row - NB) * NH;
    dst = K3 + (size_t)(row - NB) * NH;
    plane = NP * NH;
  }
  float4 v = ((const float4*)src)[tid];
  float s = v.x * v.x + v.y * v.y + v.z * v.z + v.w * v.w;
#pragma unroll
  for (int off = 32; off; off >>= 1) s += __shfl_xor(s, off);
  __shared__ float ws[4];
  if ((tid & 63) == 0) ws[tid >> 6] = s;
  __syncthreads();
  float total = ws[0] + ws[1] + ws[2] + ws[3];
  const float inv = 1.f / fmaxf(sqrtf(total), EPSF);

  float x[4] = {v.x * inv, v.y * inv, v.z * inv, v.w * inv};
  u16 t0[4], t1[4], t2[4];
#pragma unroll
  for (int i = 0; i < 4; ++i) {
    float f = x[i];
    u16 b0 = f2bf(f);        float r1 = f - bf2f(b0);
    u16 b1 = f2bf(r1);       float r2 = r1 - bf2f(b1);
    u16 b2 = f2bf(r2);
    t0[i] = b0; t1[i] = b1; t2[i] = b2;
  }
  ushort4* d0 = (ushort4*)(dst + tid * 4);
  ushort4* d1 = (ushort4*)(dst + plane + tid * 4);
  ushort4* d2 = (ushort4*)(dst + 2 * plane + tid * 4);
  *d0 = make_ushort4(t0[0], t0[1], t0[2], t0[3]);
  *d1 = make_ushort4(t1[0], t1[1], t1[2], t1[3]);
  *d2 = make_ushort4(t2[0], t2[1], t2[2], t2[3]);
}

// ---------------- Kernel 2: sim via bf16 MFMA, 6-term split product ----------------
__global__ __launch_bounds__(256) void sim_mfma_kernel(
    const u16* __restrict__ Q3, const u16* __restrict__ K3,
    float* __restrict__ sim) {
  const int bm = blockIdx.x;
  const int bn = blockIdx.y;
  const int wave = threadIdx.x >> 6;
  const int lane = threadIdx.x & 63;
  const int r0 = bm * 32 + (wave & 1) * 16;
  const int c0 = bn * 32 + (wave >> 1) * 16;
  const int koff = (lane >> 4) * 8;

  const u16* aB = Q3 + (size_t)(r0 + (lane & 15)) * NH + koff;
  const u16* bB = K3 + (size_t)(c0 + (lane & 15)) * NH + koff;
  const int QP = NB * NH, KP = NP * NH;

  f32x4 acc0 = {0.f, 0.f, 0.f, 0.f};
  f32x4 acc1 = {0.f, 0.f, 0.f, 0.f};

  for (int kc = 0; kc < NH; kc += 64) {
    s16x8 a00 = *(const s16x8*)(aB + kc);
    s16x8 a01 = *(const s16x8*)(aB + QP + kc);
    s16x8 a02 = *(const s16x8*)(aB + 2 * QP + kc);
    s16x8 b00 = *(const s16x8*)(bB + kc);
    s16x8 b01 = *(const s16x8*)(bB + KP + kc);
    s16x8 b02 = *(const s16x8*)(bB + 2 * KP + kc);
    s16x8 a10 = *(const s16x8*)(aB + kc + 32);
    s16x8 a11 = *(const s16x8*)(aB + QP + kc + 32);
    s16x8 a12 = *(const s16x8*)(aB + 2 * QP + kc + 32);
    s16x8 b10 = *(const s16x8*)(bB + kc + 32);
    s16x8 b11 = *(const s16x8*)(bB + KP + kc + 32);
    s16x8 b12 = *(const s16x8*)(bB + 2 * KP + kc + 32);

    acc0 = __builtin_amdgcn_mfma_f32_16x16x32_bf16(a00, b00, acc0, 0, 0, 0);
    acc1 = __builtin_amdgcn_mfma_f32_16x16x32_bf16(a10, b10, acc1, 0, 0, 0);
    acc0 = __builtin_amdgcn_mfma_f32_16x16x32_bf16(a00, b01, acc0, 0, 0, 0);
    acc1 = __builtin_amdgcn_mfma_f32_16x16x32_bf16(a10, b11, acc1, 0, 0, 0);
    acc0 = __builtin_amdgcn_mfma_f32_16x16x32_bf16(a01, b00, acc0, 0, 0, 0);
    acc1 = __builtin_amdgcn_mfma_f32_16x16x32_bf16(a11, b10, acc1, 0, 0, 0);
    acc0 = __builtin_amdgcn_mfma_f32_16x16x32_bf16(a01, b01, acc0, 0, 0, 0);
    acc1 = __builtin_amdgcn_mfma_f32_16x16x32_bf16(a11, b11, acc1, 0, 0, 0);
    acc0 = __builtin_amdgcn_mfma_f32_16x16x32_bf16(a00, b02, acc0, 0, 0, 0);
    acc1 = __builtin_amdgcn_mfma_f32_16x16x32_bf16(a10, b12, acc1, 0, 0, 0);
    acc0 = __builtin_amdgcn_mfma_f32_16x16x32_bf16(a02, b00, acc0, 0, 0, 0);
    acc1 = __builtin_amdgcn_mfma_f32_16x16x32_bf16(a12, b10, acc1, 0, 0, 0);
  }

#pragma unroll
  for (int i = 0; i < 4; ++i) {
    int row = r0 + (lane >> 4) * 4 + i;
    int col = c0 + (lane & 15);
    sim[(size_t)row * NP + col] = acc0[i] + acc1[i];
  }
}

// ---------------- Kernel 3: per-row top-8 ----------------
__global__ __launch_bounds__(256) void topk_kernel(
    const float* __restrict__ sim, float* __restrict__ top_sim, int* __restrict__ top_idx) {
  int row = blockIdx.x * 4 + (threadIdx.x >> 6);
  int lane = threadIdx.x & 63;
  if (row >= NB) return;

  float vals[NP / 64];
#pragma unroll
  for (int i = 0; i < NP / 64; ++i) vals[i] = sim[(size_t)row * NP + lane + i * 64];

  for (int t = 0; t < NK; ++t) {
    float bv = vals[0];
    int bi = 0;
#pragma unroll
    for (int i = 1; i < NP / 64; ++i) {
      if (vals[i] > bv) { bv = vals[i]; bi = i; }
    }
    float v = bv;
    int p = lane + bi * 64;
#pragma unroll
    for (int off = 32; off; off >>= 1) {
      float ov = __shfl_xor(v, off);
      int op = __shfl_xor(p, off);
      if (ov > v || (ov == v && op < p)) { v = ov; p = op; }
    }
    if (lane == 0) {
      top_sim[row * NK + t] = v;
      top_idx[row * NK + t] = p;
    }
    if ((p & 63) == lane) {
      int wi = p >> 6;
#pragma unroll
      for (int i = 0; i < NP / 64; ++i)
        if (i == wi) vals[i] = -INFINITY;
    }
  }
}

// ---------------- Kernel 3.5: counting-sort; order packed as (slot<<16)|p ----------------
__global__ __launch_bounds__(512) void sortperm_kernel(
    const int* __restrict__ idx, int* __restrict__ order) {
  __shared__ int hist[NP];
  __shared__ int offs[NP];
  const int t = threadIdx.x;
  hist[t] = 0;
  __syncthreads();
  for (int i = t; i < NBK; i += 512) atomicAdd(&hist[idx[i]], 1);
  __syncthreads();
  int sum = 0;
  for (int i = 0; i < t; ++i) sum += hist[i];
  offs[t] = sum;
  __syncthreads();
  for (int i = t; i < NBK; i += 512) {
    int p = idx[i];
    int pos = atomicAdd(&offs[p], 1);
    order[pos] = (i << 16) | p;  // pack slot and pool index
  }
}

// ---------------- Kernel 4: gather, p-sorted + XCD-chunked dispatch ----------------
// Dispatch id d -> sorted slot s = (d&7)*1024 + (d>>3): consecutive sorted slots
// (same pool slice) land on ONE XCD, whose L2 serves the ~15 re-reads.
__global__ __launch_bounds__(256) void gather_sorted(
    const float* __restrict__ prompts, const int* __restrict__ order,
    float* __restrict__ out, int skip_slice) {
  const int d = blockIdx.x;
  const int s = (d & 7) * (NBK / 8) + (d >> 3);
  const int packed = order[s];
  const int j = packed >> 16;
  if (j == skip_slice) return;
  const int p = packed & 0xFFFF;
  const f32x4* __restrict__ src = (const f32x4*)(prompts + (size_t)p * SLICE);
  f32x4* __restrict__ dst = (f32x4*)(out + (size_t)j * SLICE);
  const int t = threadIdx.x;
#pragma unroll
  for (int i = 0; i < (SLICE / 4) / 256; ++i) {
    f32x4 v = src[t + i * 256];
    __builtin_nontemporal_store(v, &dst[t + i * 256]);
  }
}

// ---------------- Kernel 4b (fallback only): copy the scratch-holding slice ----------------
__global__ __launch_bounds__(256) void gather_tail(
    const float* __restrict__ prompts, const int* __restrict__ idx,
    float* __restrict__ out, int j) {
  const int p = idx[j];
  __syncthreads();
  const f32x4* __restrict__ src = (const f32x4*)(prompts + (size_t)p * SLICE);
  f32x4* __restrict__ dst = (f32x4*)(out + (size_t)j * SLICE);
  const int t = threadIdx.x;
#pragma unroll
  for (int i = 0; i < (SLICE / 4) / 256; ++i) {
    f32x4 v = src[t + i * 256];
    __builtin_nontemporal_store(v, &dst[t + i * 256]);
  }
}

extern "C" void kernel_launch(void* const* d_in, const int* in_sizes, int n_in,
                              void* d_out, int out_size, void* d_ws, size_t ws_size,
                              hipStream_t stream) {
  const float* querys = (const float*)d_in[0];
  const float* prompts_key = (const float*)d_in[1];
  const float* prompts = (const float*)d_in[2];
  float* out = (float*)d_out;

  const size_t GATHER = (size_t)NBK * SLICE;
  float* top_sim = out + GATHER;

  float* sim = out;
  u16* Q3 = (u16*)(out + 524288);
  u16* K3 = (u16*)(out + 2097152);

  int* idx;
  int* order;
  int skip_slice;
  if (ws_size >= 2 * NBK * sizeof(int)) {
    idx = (int*)d_ws;
    order = idx + NBK;
    skip_slice = -1;
  } else {
    idx = (int*)(out + (size_t)(NBK - 2) * SLICE);
    order = idx + NBK;
    skip_slice = NBK - 2;
  }

  convert_kernel<<<NB + NP, 256, 0, stream>>>(querys, prompts_key, Q3, K3);

  dim3 gsim(NB / 32, NP / 32);
  sim_mfma_kernel<<<gsim, 256, 0, stream>>>(Q3, K3, sim);

  topk_kernel<<<NB / 4, 256, 0, stream>>>(sim, top_sim, idx);

  sortperm_kernel<<<1, 512, 0, stream>>>(idx, order);

  gather_sorted<<<NBK, 256, 0, stream>>>(prompts, order, out, skip_slice);

  if (skip_slice >= 0) {
    gather_tail<<<1, 256, 0, stream>>>(prompts, idx, out, skip_slice);
  }
}

// Round 6
// 276.922 us; speedup vs baseline: 1.0918x; 1.0575x over previous
//
#include <hip/hip_runtime.h>
#include <math.h>

#define NB 1024      // batch (queries)
#define NP 512       // pool size
#define NH 1024      // hidden
#define NK 8         // topk
#define NL 32        // pre_seq_len
#define NBK (NB * NK)
#define SLICE (NL * NH)   // floats per output slice (32768 = 128 KB)
#define EPSF 1e-8f
#define GG 8              // sorted slots per gather block
#define CH 8              // chunks per slice
#define CHUNK (SLICE / CH)  // 4096 floats = 16 KB

typedef float f32x4 __attribute__((ext_vector_type(4)));
typedef short s16x8 __attribute__((ext_vector_type(8)));
typedef unsigned short u16;

// ---- manual bf16 helpers (RNE) ----
__device__ __forceinline__ u16 f2bf(float x) {
  union { float f; unsigned u; } v; v.f = x;
  unsigned r = (v.u + 0x7FFFu + ((v.u >> 16) & 1u)) >> 16;
  return (u16)r;
}
__device__ __forceinline__ float bf2f(u16 b) {
  union { unsigned u; float f; } v; v.u = ((unsigned)b) << 16;
  return v.f;
}

// ---------------- Kernel 1: normalize + 3-term bf16 split ----------------
__global__ __launch_bounds__(256) void convert_kernel(
    const float* __restrict__ q, const float* __restrict__ pk,
    u16* __restrict__ Q3, u16* __restrict__ K3) {
  const int row = blockIdx.x;
  const int tid = threadIdx.x;
  const float* src;
  u16* dst;
  int plane;
  if (row < NB) {
    src = q + (size_t)row * NH;
    dst = Q3 + (size_t)row * NH;
    plane = NB * NH;
  } else {
    src = pk + (size_t)(row - NB) * NH;
    dst = K3 + (size_t)(row - NB) * NH;
    plane = NP * NH;
  }
  float4 v = ((const float4*)src)[tid];
  float s = v.x * v.x + v.y * v.y + v.z * v.z + v.w * v.w;
#pragma unroll
  for (int off = 32; off; off >>= 1) s += __shfl_xor(s, off);
  __shared__ float ws[4];
  if ((tid & 63) == 0) ws[tid >> 6] = s;
  __syncthreads();
  float total = ws[0] + ws[1] + ws[2] + ws[3];
  const float inv = 1.f / fmaxf(sqrtf(total), EPSF);

  float x[4] = {v.x * inv, v.y * inv, v.z * inv, v.w * inv};
  u16 t0[4], t1[4], t2[4];
#pragma unroll
  for (int i = 0; i < 4; ++i) {
    float f = x[i];
    u16 b0 = f2bf(f);        float r1 = f - bf2f(b0);
    u16 b1 = f2bf(r1);       float r2 = r1 - bf2f(b1);
    u16 b2 = f2bf(r2);
    t0[i] = b0; t1[i] = b1; t2[i] = b2;
  }
  ushort4* d0 = (ushort4*)(dst + tid * 4);
  ushort4* d1 = (ushort4*)(dst + plane + tid * 4);
  ushort4* d2 = (ushort4*)(dst + 2 * plane + tid * 4);
  *d0 = make_ushort4(t0[0], t0[1], t0[2], t0[3]);
  *d1 = make_ushort4(t1[0], t1[1], t1[2], t1[3]);
  *d2 = make_ushort4(t2[0], t2[1], t2[2], t2[3]);
}

// ---------------- Kernel 2: sim via bf16 MFMA, 6-term split product ----------------
__global__ __launch_bounds__(256) void sim_mfma_kernel(
    const u16* __restrict__ Q3, const u16* __restrict__ K3,
    float* __restrict__ sim) {
  const int bm = blockIdx.x;
  const int bn = blockIdx.y;
  const int wave = threadIdx.x >> 6;
  const int lane = threadIdx.x & 63;
  const int r0 = bm * 32 + (wave & 1) * 16;
  const int c0 = bn * 32 + (wave >> 1) * 16;
  const int koff = (lane >> 4) * 8;

  const u16* aB = Q3 + (size_t)(r0 + (lane & 15)) * NH + koff;
  const u16* bB = K3 + (size_t)(c0 + (lane & 15)) * NH + koff;
  const int QP = NB * NH, KP = NP * NH;

  f32x4 acc0 = {0.f, 0.f, 0.f, 0.f};
  f32x4 acc1 = {0.f, 0.f, 0.f, 0.f};

  for (int kc = 0; kc < NH; kc += 64) {
    s16x8 a00 = *(const s16x8*)(aB + kc);
    s16x8 a01 = *(const s16x8*)(aB + QP + kc);
    s16x8 a02 = *(const s16x8*)(aB + 2 * QP + kc);
    s16x8 b00 = *(const s16x8*)(bB + kc);
    s16x8 b01 = *(const s16x8*)(bB + KP + kc);
    s16x8 b02 = *(const s16x8*)(bB + 2 * KP + kc);
    s16x8 a10 = *(const s16x8*)(aB + kc + 32);
    s16x8 a11 = *(const s16x8*)(aB + QP + kc + 32);
    s16x8 a12 = *(const s16x8*)(aB + 2 * QP + kc + 32);
    s16x8 b10 = *(const s16x8*)(bB + kc + 32);
    s16x8 b11 = *(const s16x8*)(bB + KP + kc + 32);
    s16x8 b12 = *(const s16x8*)(bB + 2 * KP + kc + 32);

    acc0 = __builtin_amdgcn_mfma_f32_16x16x32_bf16(a00, b00, acc0, 0, 0, 0);
    acc1 = __builtin_amdgcn_mfma_f32_16x16x32_bf16(a10, b10, acc1, 0, 0, 0);
    acc0 = __builtin_amdgcn_mfma_f32_16x16x32_bf16(a00, b01, acc0, 0, 0, 0);
    acc1 = __builtin_amdgcn_mfma_f32_16x16x32_bf16(a10, b11, acc1, 0, 0, 0);
    acc0 = __builtin_amdgcn_mfma_f32_16x16x32_bf16(a01, b00, acc0, 0, 0, 0);
    acc1 = __builtin_amdgcn_mfma_f32_16x16x32_bf16(a11, b10, acc1, 0, 0, 0);
    acc0 = __builtin_amdgcn_mfma_f32_16x16x32_bf16(a01, b01, acc0, 0, 0, 0);
    acc1 = __builtin_amdgcn_mfma_f32_16x16x32_bf16(a11, b11, acc1, 0, 0, 0);
    acc0 = __builtin_amdgcn_mfma_f32_16x16x32_bf16(a00, b02, acc0, 0, 0, 0);
    acc1 = __builtin_amdgcn_mfma_f32_16x16x32_bf16(a10, b12, acc1, 0, 0, 0);
    acc0 = __builtin_amdgcn_mfma_f32_16x16x32_bf16(a02, b00, acc0, 0, 0, 0);
    acc1 = __builtin_amdgcn_mfma_f32_16x16x32_bf16(a12, b10, acc1, 0, 0, 0);
  }

#pragma unroll
  for (int i = 0; i < 4; ++i) {
    int row = r0 + (lane >> 4) * 4 + i;
    int col = c0 + (lane & 15);
    sim[(size_t)row * NP + col] = acc0[i] + acc1[i];
  }
}

// ---------------- Kernel 3: per-row top-8 ----------------
__global__ __launch_bounds__(256) void topk_kernel(
    const float* __restrict__ sim, float* __restrict__ top_sim, int* __restrict__ top_idx) {
  int row = blockIdx.x * 4 + (threadIdx.x >> 6);
  int lane = threadIdx.x & 63;
  if (row >= NB) return;

  float vals[NP / 64];
#pragma unroll
  for (int i = 0; i < NP / 64; ++i) vals[i] = sim[(size_t)row * NP + lane + i * 64];

  for (int t = 0; t < NK; ++t) {
    float bv = vals[0];
    int bi = 0;
#pragma unroll
    for (int i = 1; i < NP / 64; ++i) {
      if (vals[i] > bv) { bv = vals[i]; bi = i; }
    }
    float v = bv;
    int p = lane + bi * 64;
#pragma unroll
    for (int off = 32; off; off >>= 1) {
      float ov = __shfl_xor(v, off);
      int op = __shfl_xor(p, off);
      if (ov > v || (ov == v && op < p)) { v = ov; p = op; }
    }
    if (lane == 0) {
      top_sim[row * NK + t] = v;
      top_idx[row * NK + t] = p;
    }
    if ((p & 63) == lane) {
      int wi = p >> 6;
#pragma unroll
      for (int i = 0; i < NP / 64; ++i)
        if (i == wi) vals[i] = -INFINITY;
    }
  }
}

// ---------------- Kernel 3.5: counting-sort; order packed as (slot<<16)|p ----------------
__global__ __launch_bounds__(512) void sortperm_kernel(
    const int* __restrict__ idx, int* __restrict__ order) {
  __shared__ int hist[NP];
  __shared__ int offs[NP];
  const int t = threadIdx.x;
  hist[t] = 0;
  __syncthreads();
  for (int i = t; i < NBK; i += 512) atomicAdd(&hist[idx[i]], 1);
  __syncthreads();
  int sum = 0;
  for (int i = 0; i < t; ++i) sum += hist[i];
  offs[t] = sum;
  __syncthreads();
  for (int i = t; i < NBK; i += 512) {
    int p = idx[i];
    int pos = atomicAdd(&offs[p], 1);
    order[pos] = (i << 16) | p;  // pack slot and pool index
  }
}

// ---------------- Kernel 4: broadcast gather ----------------
// Block = (group of GG p-sorted slots) x (16 KB chunk). Load the chunk into
// registers once per distinct p (usually once/block), nt-store to GG slices.
// Dispatch d: xcd = d&7 owns a contiguous range of groups -> L2 read reuse.
__global__ __launch_bounds__(256) void gather_bcast(
    const float* __restrict__ prompts, const int* __restrict__ order,
    float* __restrict__ out, int skip_slice) {
  const int d = blockIdx.x;
  const int xcd = d & 7;
  const int i = d >> 3;            // 0..1023
  const int gl = i >> 3;           // group-local on this XCD (0..127)
  const int c = i & 7;             // chunk 0..7
  const int g = xcd * (NBK / GG / 8) + gl;  // global group 0..1023
  const int t = threadIdx.x;
  const int base = c * CHUNK + t * 4;  // float offset of round-0 f32x4

  f32x4 r0, r1, r2, r3;
  int pprev = -1;
#pragma unroll
  for (int k = 0; k < GG; ++k) {
    const int packed = order[g * GG + k];
    const int j = packed >> 16;
    const int p = packed & 0xFFFF;
    if (p != pprev) {  // block-uniform branch
      const f32x4* src = (const f32x4*)(prompts + (size_t)p * SLICE + base);
      r0 = src[0]; r1 = src[256]; r2 = src[512]; r3 = src[768];
      pprev = p;
    }
    if (j == skip_slice) continue;
    f32x4* dst = (f32x4*)(out + (size_t)j * SLICE + base);
    __builtin_nontemporal_store(r0, &dst[0]);
    __builtin_nontemporal_store(r1, &dst[256]);
    __builtin_nontemporal_store(r2, &dst[512]);
    __builtin_nontemporal_store(r3, &dst[768]);
  }
}

// ---------------- Kernel 4b (fallback only): copy the scratch-holding slice ----------------
__global__ __launch_bounds__(256) void gather_tail(
    const float* __restrict__ prompts, const int* __restrict__ idx,
    float* __restrict__ out, int j) {
  const int p = idx[j];
  __syncthreads();
  const f32x4* __restrict__ src = (const f32x4*)(prompts + (size_t)p * SLICE);
  f32x4* __restrict__ dst = (f32x4*)(out + (size_t)j * SLICE);
  const int t = threadIdx.x;
#pragma unroll
  for (int i = 0; i < (SLICE / 4) / 256; ++i) {
    f32x4 v = src[t + i * 256];
    __builtin_nontemporal_store(v, &dst[t + i * 256]);
  }
}

extern "C" void kernel_launch(void* const* d_in, const int* in_sizes, int n_in,
                              void* d_out, int out_size, void* d_ws, size_t ws_size,
                              hipStream_t stream) {
  const float* querys = (const float*)d_in[0];
  const float* prompts_key = (const float*)d_in[1];
  const float* prompts = (const float*)d_in[2];
  float* out = (float*)d_out;

  const size_t GATHER = (size_t)NBK * SLICE;
  float* top_sim = out + GATHER;

  float* sim = out;
  u16* Q3 = (u16*)(out + 524288);
  u16* K3 = (u16*)(out + 2097152);

  int* idx;
  int* order;
  int skip_slice;
  if (ws_size >= 2 * NBK * sizeof(int)) {
    idx = (int*)d_ws;
    order = idx + NBK;
    skip_slice = -1;
  } else {
    idx = (int*)(out + (size_t)(NBK - 2) * SLICE);
    order = idx + NBK;
    skip_slice = NBK - 2;
  }

  convert_kernel<<<NB + NP, 256, 0, stream>>>(querys, prompts_key, Q3, K3);

  dim3 gsim(NB / 32, NP / 32);
  sim_mfma_kernel<<<gsim, 256, 0, stream>>>(Q3, K3, sim);

  topk_kernel<<<NB / 4, 256, 0, stream>>>(sim, top_sim, idx);

  sortperm_kernel<<<1, 512, 0, stream>>>(idx, order);

  gather_bcast<<<(NBK / GG) * CH, 256, 0, stream>>>(prompts, order, out, skip_slice);

  if (skip_slice >= 0) {
    gather_tail<<<1, 256, 0, stream>>>(prompts, idx, out, skip_slice);
  }
}

// Round 8
// 269.136 us; speedup vs baseline: 1.1233x; 1.0289x over previous
//
#include <hip/hip_runtime.h>
#include <math.h>

#define NB 1024      // batch (queries)
#define NP 512       // pool size
#define NH 1024      // hidden
#define NK 8         // topk
#define NL 32        // pre_seq_len
#define NBK (NB * NK)
#define SLICE (NL * NH)   // floats per output slice (32768 = 128 KB)
#define EPSF 1e-8f
#define GG 8              // sorted slots per gather block
#define CH 8              // chunks per slice
#define CHUNK (SLICE / CH)  // 4096 floats = 16 KB

typedef float f32x4 __attribute__((ext_vector_type(4)));
typedef short s16x8 __attribute__((ext_vector_type(8)));
typedef unsigned short u16;

// ---- manual bf16 helpers (RNE) ----
__device__ __forceinline__ u16 f2bf(float x) {
  union { float f; unsigned u; } v; v.f = x;
  unsigned r = (v.u + 0x7FFFu + ((v.u >> 16) & 1u)) >> 16;
  return (u16)r;
}
__device__ __forceinline__ float bf2f(u16 b) {
  union { unsigned u; float f; } v; v.u = ((unsigned)b) << 16;
  return v.f;
}

// ---------------- Kernel 1: normalize + 3-term bf16 split (PLANAR, as in R6) ----------------
// X3[t][row][h], t=0,1,2;  x ~= x0+x1+x2.
__global__ __launch_bounds__(256) void convert_kernel(
    const float* __restrict__ q, const float* __restrict__ pk,
    u16* __restrict__ Q3, u16* __restrict__ K3) {
  const int row = blockIdx.x;
  const int tid = threadIdx.x;
  const float* src;
  u16* dst;
  int plane;
  if (row < NB) {
    src = q + (size_t)row * NH;
    dst = Q3 + (size_t)row * NH;
    plane = NB * NH;
  } else {
    src = pk + (size_t)(row - NB) * NH;
    dst = K3 + (size_t)(row - NB) * NH;
    plane = NP * NH;
  }
  float4 v = ((const float4*)src)[tid];
  float s = v.x * v.x + v.y * v.y + v.z * v.z + v.w * v.w;
#pragma unroll
  for (int off = 32; off; off >>= 1) s += __shfl_xor(s, off);
  __shared__ float ws[4];
  if ((tid & 63) == 0) ws[tid >> 6] = s;
  __syncthreads();
  float total = ws[0] + ws[1] + ws[2] + ws[3];
  const float inv = 1.f / fmaxf(sqrtf(total), EPSF);

  float x[4] = {v.x * inv, v.y * inv, v.z * inv, v.w * inv};
  u16 t0[4], t1[4], t2[4];
#pragma unroll
  for (int i = 0; i < 4; ++i) {
    float f = x[i];
    u16 b0 = f2bf(f);        float r1 = f - bf2f(b0);
    u16 b1 = f2bf(r1);       float r2 = r1 - bf2f(b1);
    u16 b2 = f2bf(r2);
    t0[i] = b0; t1[i] = b1; t2[i] = b2;
  }
  *(ushort4*)(dst + tid * 4)             = make_ushort4(t0[0], t0[1], t0[2], t0[3]);
  *(ushort4*)(dst + plane + tid * 4)     = make_ushort4(t1[0], t1[1], t1[2], t1[3]);
  *(ushort4*)(dst + 2 * plane + tid * 4) = make_ushort4(t2[0], t2[1], t2[2], t2[3]);
}

// ---------------- Kernel 2: sim via bf16 MFMA, 6-term split (R6 math, 32x32/wave) ----------------
// Block = 2 waves. Each wave: 32x32 output tile = 2 row-sets x 2 col-sets.
// Per 32-k chunk: 12 fragment loads (2x3 A + 2x3 B planes), 24 MFMA (6 terms x 4 quadrants).
// Terms: a0b0, a0b1, a1b0, a1b1, a0b2, a2b0 (error ~2^-26) — validated R4-R6.
__global__ __launch_bounds__(128) void sim_mfma_kernel(
    const u16* __restrict__ Q3, const u16* __restrict__ K3,
    float* __restrict__ sim) {
  const int bm = blockIdx.x;            // 32 row tiles of 32
  const int wave = threadIdx.x >> 6;    // 0..1
  const int lane = threadIdx.x & 63;
  const int r0 = bm * 32;
  const int c0 = blockIdx.y * 64 + wave * 32;
  const int koff = (lane >> 4) * 8;
  const int QP = NB * NH, KP = NP * NH;

  const u16* aR0 = Q3 + (size_t)(r0 + (lane & 15)) * NH + koff;  // rows r0..r0+15
  const u16* aR1 = aR0 + 16 * NH;                                 // rows r0+16..r0+31
  const u16* bC0 = K3 + (size_t)(c0 + (lane & 15)) * NH + koff;  // cols c0..c0+15
  const u16* bC1 = bC0 + 16 * NH;                                 // cols c0+16..c0+31

  f32x4 acc00 = {0,0,0,0}, acc01 = {0,0,0,0}, acc10 = {0,0,0,0}, acc11 = {0,0,0,0};

  for (int kc = 0; kc < NH; kc += 32) {
    s16x8 a00 = *(const s16x8*)(aR0 + kc);            // row-set0 plane0
    s16x8 a01 = *(const s16x8*)(aR0 + QP + kc);       // plane1
    s16x8 a02 = *(const s16x8*)(aR0 + 2 * QP + kc);   // plane2
    s16x8 a10 = *(const s16x8*)(aR1 + kc);
    s16x8 a11 = *(const s16x8*)(aR1 + QP + kc);
    s16x8 a12 = *(const s16x8*)(aR1 + 2 * QP + kc);
    s16x8 b00 = *(const s16x8*)(bC0 + kc);
    s16x8 b01 = *(const s16x8*)(bC0 + KP + kc);
    s16x8 b02 = *(const s16x8*)(bC0 + 2 * KP + kc);
    s16x8 b10 = *(const s16x8*)(bC1 + kc);
    s16x8 b11 = *(const s16x8*)(bC1 + KP + kc);
    s16x8 b12 = *(const s16x8*)(bC1 + 2 * KP + kc);

    // term a0*b0 (4 quadrants — independent accs, good ILP)
    acc00 = __builtin_amdgcn_mfma_f32_16x16x32_bf16(a00, b00, acc00, 0, 0, 0);
    acc01 = __builtin_amdgcn_mfma_f32_16x16x32_bf16(a00, b10, acc01, 0, 0, 0);
    acc10 = __builtin_amdgcn_mfma_f32_16x16x32_bf16(a10, b00, acc10, 0, 0, 0);
    acc11 = __builtin_amdgcn_mfma_f32_16x16x32_bf16(a10, b10, acc11, 0, 0, 0);
    // term a0*b1
    acc00 = __builtin_amdgcn_mfma_f32_16x16x32_bf16(a00, b01, acc00, 0, 0, 0);
    acc01 = __builtin_amdgcn_mfma_f32_16x16x32_bf16(a00, b11, acc01, 0, 0, 0);
    acc10 = __builtin_amdgcn_mfma_f32_16x16x32_bf16(a10, b01, acc10, 0, 0, 0);
    acc11 = __builtin_amdgcn_mfma_f32_16x16x32_bf16(a10, b11, acc11, 0, 0, 0);
    // term a1*b0
    acc00 = __builtin_amdgcn_mfma_f32_16x16x32_bf16(a01, b00, acc00, 0, 0, 0);
    acc01 = __builtin_amdgcn_mfma_f32_16x16x32_bf16(a01, b10, acc01, 0, 0, 0);
    acc10 = __builtin_amdgcn_mfma_f32_16x16x32_bf16(a11, b00, acc10, 0, 0, 0);
    acc11 = __builtin_amdgcn_mfma_f32_16x16x32_bf16(a11, b10, acc11, 0, 0, 0);
    // term a1*b1
    acc00 = __builtin_amdgcn_mfma_f32_16x16x32_bf16(a01, b01, acc00, 0, 0, 0);
    acc01 = __builtin_amdgcn_mfma_f32_16x16x32_bf16(a01, b11, acc01, 0, 0, 0);
    acc10 = __builtin_amdgcn_mfma_f32_16x16x32_bf16(a11, b01, acc10, 0, 0, 0);
    acc11 = __builtin_amdgcn_mfma_f32_16x16x32_bf16(a11, b11, acc11, 0, 0, 0);
    // term a0*b2
    acc00 = __builtin_amdgcn_mfma_f32_16x16x32_bf16(a00, b02, acc00, 0, 0, 0);
    acc01 = __builtin_amdgcn_mfma_f32_16x16x32_bf16(a00, b12, acc01, 0, 0, 0);
    acc10 = __builtin_amdgcn_mfma_f32_16x16x32_bf16(a10, b02, acc10, 0, 0, 0);
    acc11 = __builtin_amdgcn_mfma_f32_16x16x32_bf16(a10, b12, acc11, 0, 0, 0);
    // term a2*b0
    acc00 = __builtin_amdgcn_mfma_f32_16x16x32_bf16(a02, b00, acc00, 0, 0, 0);
    acc01 = __builtin_amdgcn_mfma_f32_16x16x32_bf16(a02, b10, acc01, 0, 0, 0);
    acc10 = __builtin_amdgcn_mfma_f32_16x16x32_bf16(a12, b00, acc10, 0, 0, 0);
    acc11 = __builtin_amdgcn_mfma_f32_16x16x32_bf16(a12, b10, acc11, 0, 0, 0);
  }

  const int rr = (lane >> 4) * 4;
  const int cc = lane & 15;
#pragma unroll
  for (int i = 0; i < 4; ++i) {
    float* s0 = &sim[(size_t)(r0 + rr + i) * NP + c0 + cc];
    float* s1 = &sim[(size_t)(r0 + 16 + rr + i) * NP + c0 + cc];
    s0[0]  = acc00[i];
    s0[16] = acc01[i];
    s1[0]  = acc10[i];
    s1[16] = acc11[i];
  }
}

// ---------------- Kernel 3: per-row top-8 (sorted desc, tie -> lower index) ----------------
__global__ __launch_bounds__(256) void topk_kernel(
    const float* __restrict__ sim, float* __restrict__ top_sim, int* __restrict__ top_idx) {
  int row = blockIdx.x * 4 + (threadIdx.x >> 6);
  int lane = threadIdx.x & 63;
  if (row >= NB) return;

  float vals[NP / 64];
#pragma unroll
  for (int i = 0; i < NP / 64; ++i) vals[i] = sim[(size_t)row * NP + lane + i * 64];

  for (int t = 0; t < NK; ++t) {
    float bv = vals[0];
    int bi = 0;
#pragma unroll
    for (int i = 1; i < NP / 64; ++i) {
      if (vals[i] > bv) { bv = vals[i]; bi = i; }
    }
    float v = bv;
    int p = lane + bi * 64;
#pragma unroll
    for (int off = 32; off; off >>= 1) {
      float ov = __shfl_xor(v, off);
      int op = __shfl_xor(p, off);
      if (ov > v || (ov == v && op < p)) { v = ov; p = op; }
    }
    if (lane == 0) {
      top_sim[row * NK + t] = v;
      top_idx[row * NK + t] = p;
    }
    if ((p & 63) == lane) {
      int wi = p >> 6;
#pragma unroll
      for (int i = 0; i < NP / 64; ++i)
        if (i == wi) vals[i] = -INFINITY;
    }
  }
}

// ---------------- Kernel 3.5: counting-sort; order packed as (slot<<16)|p ----------------
__global__ __launch_bounds__(512) void sortperm_kernel(
    const int* __restrict__ idx, int* __restrict__ order) {
  __shared__ int hist[NP];
  __shared__ int offs[NP];
  const int t = threadIdx.x;
  hist[t] = 0;
  __syncthreads();
  for (int i = t; i < NBK; i += 512) atomicAdd(&hist[idx[i]], 1);
  __syncthreads();
  int sum = 0;
  for (int i = 0; i < t; ++i) sum += hist[i];
  offs[t] = sum;
  __syncthreads();
  for (int i = t; i < NBK; i += 512) {
    int p = idx[i];
    int pos = atomicAdd(&offs[p], 1);
    order[pos] = (i << 16) | p;  // pack slot and pool index
  }
}

// ---------------- Kernel 4: broadcast gather ----------------
// Block = (group of GG p-sorted slots) x (16 KB chunk). Two int4 loads fetch all
// 8 packed (j,p); chunk loaded into regs once per distinct p, nt-stored to GG dsts.
// Dispatch d: xcd = d&7 owns a contiguous range of groups -> L2 read reuse.
__global__ __launch_bounds__(256) void gather_bcast(
    const float* __restrict__ prompts, const int* __restrict__ order,
    float* __restrict__ out, int skip_slice) {
  const int d = blockIdx.x;
  const int xcd = d & 7;
  const int i = d >> 3;            // 0..1023
  const int gl = i >> 3;           // group-local on this XCD (0..127)
  const int c = i & 7;             // chunk 0..7
  const int g = xcd * (NBK / GG / 8) + gl;  // global group 0..1023
  const int t = threadIdx.x;
  const int base = c * CHUNK + t * 4;  // float offset of round-0 f32x4

  const int4 o0 = *(const int4*)&order[g * GG];
  const int4 o1 = *(const int4*)&order[g * GG + 4];
  const int pp[GG] = {o0.x & 0xFFFF, o0.y & 0xFFFF, o0.z & 0xFFFF, o0.w & 0xFFFF,
                      o1.x & 0xFFFF, o1.y & 0xFFFF, o1.z & 0xFFFF, o1.w & 0xFFFF};
  const int jj[GG] = {o0.x >> 16, o0.y >> 16, o0.z >> 16, o0.w >> 16,
                      o1.x >> 16, o1.y >> 16, o1.z >> 16, o1.w >> 16};

  f32x4 r0, r1, r2, r3;
  int pprev = -1;
#pragma unroll
  for (int k = 0; k < GG; ++k) {
    const int p = pp[k];
    if (p != pprev) {  // block-uniform branch
      const f32x4* src = (const f32x4*)(prompts + (size_t)p * SLICE + base);
      r0 = src[0]; r1 = src[256]; r2 = src[512]; r3 = src[768];
      pprev = p;
    }
    const int j = jj[k];
    if (j == skip_slice) continue;
    f32x4* dst = (f32x4*)(out + (size_t)j * SLICE + base);
    __builtin_nontemporal_store(r0, &dst[0]);
    __builtin_nontemporal_store(r1, &dst[256]);
    __builtin_nontemporal_store(r2, &dst[512]);
    __builtin_nontemporal_store(r3, &dst[768]);
  }
}

// ---------------- Kernel 4b (fallback only): copy the scratch-holding slice ----------------
__global__ __launch_bounds__(256) void gather_tail(
    const float* __restrict__ prompts, const int* __restrict__ idx,
    float* __restrict__ out, int j) {
  const int p = idx[j];
  __syncthreads();
  const f32x4* __restrict__ src = (const f32x4*)(prompts + (size_t)p * SLICE);
  f32x4* __restrict__ dst = (f32x4*)(out + (size_t)j * SLICE);
  const int t = threadIdx.x;
#pragma unroll
  for (int i = 0; i < (SLICE / 4) / 256; ++i) {
    f32x4 v = src[t + i * 256];
    __builtin_nontemporal_store(v, &dst[t + i * 256]);
  }
}

extern "C" void kernel_launch(void* const* d_in, const int* in_sizes, int n_in,
                              void* d_out, int out_size, void* d_ws, size_t ws_size,
                              hipStream_t stream) {
  const float* querys = (const float*)d_in[0];
  const float* prompts_key = (const float*)d_in[1];
  const float* prompts = (const float*)d_in[2];
  float* out = (float*)d_out;

  const size_t GATHER = (size_t)NBK * SLICE;
  float* top_sim = out + GATHER;

  // Front scratch (consumed before gather overwrites slices 0..87):
  //   sim [1024*512] f32 at +0 (2 MiB)
  //   Q3  [3][1024][1024] bf16 planar at float-offset 524288 (6 MiB)
  //   K3  [3][512][1024]  bf16 planar at float-offset 2097152 (3 MiB)
  float* sim = out;
  u16* Q3 = (u16*)(out + 524288);
  u16* K3 = (u16*)(out + 2097152);

  int* idx;
  int* order;
  int skip_slice;
  if (ws_size >= 2 * NBK * sizeof(int)) {
    idx = (int*)d_ws;
    order = idx + NBK;
    skip_slice = -1;
  } else {
    idx = (int*)(out + (size_t)(NBK - 2) * SLICE);
    order = idx + NBK;
    skip_slice = NBK - 2;
  }

  convert_kernel<<<NB + NP, 256, 0, stream>>>(querys, prompts_key, Q3, K3);

  dim3 gsim(NB / 32, NP / 64);  // 32 x 8, 2 waves per block
  sim_mfma_kernel<<<gsim, 128, 0, stream>>>(Q3, K3, sim);

  topk_kernel<<<NB / 4, 256, 0, stream>>>(sim, top_sim, idx);

  sortperm_kernel<<<1, 512, 0, stream>>>(idx, order);

  gather_bcast<<<(NBK / GG) * CH, 256, 0, stream>>>(prompts, order, out, skip_slice);

  if (skip_slice >= 0) {
    gather_tail<<<1, 256, 0, stream>>>(prompts, idx, out, skip_slice);
  }
}